// Round 12
// baseline (85.154 us; speedup 1.0000x reference)
//
#include <hip/hip_runtime.h>
#include <hip/hip_bf16.h>
#include <math.h>

#define BN_EPS 1e-5f

typedef __attribute__((ext_vector_type(8))) short short8;
typedef __attribute__((ext_vector_type(4))) float f32x4;

__device__ __forceinline__ unsigned short bfbits(float f) {
  __hip_bfloat16 h = __float2bfloat16(f);
  return *reinterpret_cast<unsigned short*>(&h);
}
__device__ __forceinline__ float bf2f(unsigned short u) {
  union { unsigned v; float f; } c; c.v = ((unsigned)u) << 16;
  return c.f;
}

// ---------------- Kernel A: prep (blocks 0..15) + pool (blocks 16..2063) ----
__global__ __launch_bounds__(256) void prep_pool_kernel(
    const float* __restrict__ x, float* __restrict__ pooled,
    const float* __restrict__ fc3_w,
    const float* __restrict__ g3, const float* __restrict__ b3,
    const float* __restrict__ m3, const float* __restrict__ v3,
    const float* __restrict__ c1w,
    const float* __restrict__ g1, const float* __restrict__ b1,
    const float* __restrict__ m1, const float* __restrict__ v1,
    const float* __restrict__ c3w,
    const float* __restrict__ gk, const float* __restrict__ bk,
    const float* __restrict__ mk, const float* __restrict__ vk,
    unsigned short* __restrict__ ahi, unsigned short* __restrict__ alo,
    float* __restrict__ totb) {
  int bid = blockIdx.x;
  int tid = threadIdx.x;
  if (bid < 16) {
    int s = bid >> 2;
    int o = (bid & 3) * 16 + (tid >> 4);
    int kc = (tid & 15) * 4;
    float sc3 = g3[s] * rsqrtf(v3[s] + BN_EPS);
    float sc1 = g1[s] * rsqrtf(v1[s] + BN_EPS);
    float sck = gk[s] * rsqrtf(vk[s] + BN_EPS);
    float c0 = sc1 * c1w[s] + sck * c3w[s * 9 + 4];
    int oh = o >> 3, ow = o & 7;
    unsigned short H[4], L[4];
#pragma unroll
    for (int j = 0; j < 4; ++j) {
      int k = kc + j;
      int kh = k >> 3, kw = k & 7;
      float a = sc3 * fc3_w[(s * 64 + o) * 64 + k];
      int dy = kh - oh, dx = kw - ow;
      if (dy >= -1 && dy <= 1 && dx >= -1 && dx <= 1)
        a += (dy == 0 && dx == 0) ? c0 : sck * c3w[s * 9 + (dy + 1) * 3 + (dx + 1)];
      unsigned short h = bfbits(a);
      H[j] = h;
      L[j] = bfbits(a - bf2f(h));
    }
    size_t base = (size_t)(s * 64 + o) * 64 + kc;
    *(ushort4*)(ahi + base) = make_ushort4(H[0], H[1], H[2], H[3]);
    *(ushort4*)(alo + base) = make_ushort4(L[0], L[1], L[2], L[3]);
    if (bid == 0 && tid < 4) {
      int ss = tid;
      float s3 = g3[ss] * rsqrtf(v3[ss] + BN_EPS);
      float s1 = g1[ss] * rsqrtf(v1[ss] + BN_EPS);
      float sk = gk[ss] * rsqrtf(vk[ss] + BN_EPS);
      totb[ss] = (b3[ss] - m3[ss] * s3) + (b1[ss] - m1[ss] * s1) + (bk[ss] - mk[ss] * sk);
    }
    return;
  }
  int w = tid >> 6, lane = tid & 63;
  int bc = (bid - 16) * 4 + w;
  const f32x4* xp = (const f32x4*)(x + (size_t)bc * 4096);
  float ssum = 0.f;
#pragma unroll
  for (int i = 0; i < 16; ++i) {
    f32x4 v = xp[i * 64 + lane];
    ssum += (v.x + v.y) + (v.z + v.w);
  }
#pragma unroll
  for (int m = 32; m >= 1; m >>= 1) ssum += __shfl_xor(ssum, m, 64);
  if (lane == 0) pooled[bc] = ssum * (1.f / 4096.f);
}

// ---------------- Kernel B: main — LDS-staged MFMA + fused coalesced gate --
// Grid 2048 (reversed order for L3 recency). Block = 512 thr = 8 waves.
// Pre-barrier: stage x tile (coalesced) + fc1 partials (line-walking loads).
// Post-barrier1: wave 0 computes the block's 32 gate values (hidden under
// other waves' MFMA). Barrier2 -> epilogue applies gate, NT stores.
__global__ __launch_bounds__(512, 4) void main_kernel(
    const float* __restrict__ x,
    const unsigned short* __restrict__ ahi, const unsigned short* __restrict__ alo,
    const float* __restrict__ totb, const float* __restrict__ pooled,
    const float* __restrict__ fc1_w, const float* __restrict__ fc1_b,
    const float* __restrict__ fc2_w, const float* __restrict__ fc2_b,
    float* __restrict__ out) {
  __shared__ unsigned short xs[33280];  // hi [0,16640), lo [16640,33280)
  __shared__ float partL[512];          // fc1 partials [k][h]
  __shared__ float hidL[64];
  __shared__ float gmulL[32];

  int bid = 2047 - (int)blockIdx.x;     // reversed: read x tail-first (L3-hot)
  int cgh = bid & 7;
  int hpi = (bid >> 3) & 7;
  int b   = bid >> 6;
  int tid = threadIdx.x;
  int wv  = tid >> 6;
  int lane = tid & 63;
  int s    = __builtin_amdgcn_readfirstlane(wv & 3);
  int half = __builtin_amdgcn_readfirstlane(wv >> 2);
  int r16 = tid & 15;
  int g   = (tid >> 4) & 3;

  // ---- stage: 8 batched contiguous x loads per thread ----
  f32x4 gbuf[8];
#pragma unroll
  for (int i = 0; i < 8; ++i) {
    int flat = i * 512 + tid;
    int slot = flat >> 7;
    int off  = flat & 127;
    int row  = off >> 4, w4 = off & 15;
    int c = cgh * 32 + (slot & 7) * 4 + (slot >> 3);
    gbuf[i] = *(const f32x4*)(x + (size_t)(b * 256 + c) * 4096 + (hpi * 8 + row) * 64 + w4 * 4);
  }

  // ---- fc1 partial (coalesced-ish 128B-line-walking loads), -> partL ----
  {
    int h = wv * 8 + (lane >> 3);
    int k = lane & 7;
    const float* fw = fc1_w + h * 256 + k * 32;
    const float* pp = pooled + b * 256 + k * 32;
    float pacc = 0.f;
#pragma unroll
    for (int j = 0; j < 8; ++j) {
      f32x4 w4 = *(const f32x4*)(fw + j * 4);
      f32x4 p4 = *(const f32x4*)(pp + j * 4);
      pacc += w4.x * p4.x + w4.y * p4.y + w4.z * p4.z + w4.w * p4.w;
    }
    partL[k * 64 + h] = pacc;
  }

  // ---- A fragments (L2-resident) ----
  short8 Ah[2][2], Al[2][2];  // [kt][oti]
#pragma unroll
  for (int oti = 0; oti < 2; ++oti)
#pragma unroll
    for (int kt = 0; kt < 2; ++kt) {
      size_t off = (size_t)(s * 64 + (half * 2 + oti) * 16 + r16) * 64 + kt * 32 + g * 8;
      Ah[kt][oti] = *(const short8*)(ahi + off);
      Al[kt][oti] = *(const short8*)(alo + off);
    }
  float tb = totb[s];

  // ---- convert + ds_write (hi/lo planes) ----
#pragma unroll
  for (int i = 0; i < 8; ++i) {
    int flat = i * 512 + tid;
    int slot = flat >> 7;
    int off  = flat & 127;
    int row  = off >> 4, w4 = off & 15;
    float fv[4] = {gbuf[i].x, gbuf[i].y, gbuf[i].z, gbuf[i].w};
    unsigned short h0 = bfbits(fv[0]), h1 = bfbits(fv[1]), h2 = bfbits(fv[2]), h3 = bfbits(fv[3]);
    ushort4 H = make_ushort4(h0, h1, h2, h3);
    ushort4 L = make_ushort4(bfbits(fv[0] - bf2f(h0)), bfbits(fv[1] - bf2f(h1)),
                             bfbits(fv[2] - bf2f(h2)), bfbits(fv[3] - bf2f(h3)));
    int base = slot * 520 + row * 64 + w4 * 4;
    *(ushort4*)&xs[base] = H;
    *(ushort4*)&xs[16640 + base] = L;
  }

  __syncthreads();  // barrier1: staging + fc1 partials complete

  // ---- wave 0: assemble hid, compute 32 gate values (others start MFMA) ----
  if (wv == 0) {
    float hsum = fc1_b[lane];
#pragma unroll
    for (int k2 = 0; k2 < 8; ++k2) hsum += partL[k2 * 64 + lane];
    hidL[lane] = fmaxf(hsum, 0.f);
    int r = lane >> 1, hf = lane & 1;
    const float* w2 = fc2_w + (hpi * 32 + r) * 64 + hf * 32;
    float p = 0.f;
#pragma unroll
    for (int j = 0; j < 32; j += 4) {
      f32x4 w4 = *(const f32x4*)(w2 + j);
      p += w4.x * hidL[hf * 32 + j] + w4.y * hidL[hf * 32 + j + 1]
         + w4.z * hidL[hf * 32 + j + 2] + w4.w * hidL[hf * 32 + j + 3];
    }
    p += __shfl_xor(p, 1, 64);
    float gv = 1.f / (1.f + expf(-(p + fc2_b[hpi * 32 + r])));
    if (hf == 0) gmulL[r] = gv;
  }

  // ---- MFMA loop: pure ds_read + MFMA ----
  f32x4 acc[2][4];
#pragma unroll
  for (int i = 0; i < 2; ++i)
#pragma unroll
    for (int j = 0; j < 4; ++j) acc[i][j] = f32x4{0.f, 0.f, 0.f, 0.f};

  int jch = r16 & 7;
#pragma unroll
  for (int kt = 0; kt < 2; ++kt)
#pragma unroll
    for (int nt = 0; nt < 4; ++nt) {
      int wpi = nt * 2 + (r16 >> 3);
      int addr = (s * 8 + jch) * 520 + (kt * 4 + g) * 64 + wpi * 8;
      short8 BH = *(const short8*)&xs[addr];
      short8 BL = *(const short8*)&xs[16640 + addr];
#pragma unroll
      for (int oti = 0; oti < 2; ++oti) {
        acc[oti][nt] = __builtin_amdgcn_mfma_f32_16x16x32_bf16(Ah[kt][oti], BH, acc[oti][nt], 0, 0, 0);
        acc[oti][nt] = __builtin_amdgcn_mfma_f32_16x16x32_bf16(Ah[kt][oti], BL, acc[oti][nt], 0, 0, 0);
        acc[oti][nt] = __builtin_amdgcn_mfma_f32_16x16x32_bf16(Al[kt][oti], BH, acc[oti][nt], 0, 0, 0);
      }
    }

  __syncthreads();  // barrier2: gmulL ready

  // ---- epilogue: NT stores ----
#pragma unroll
  for (int nt = 0; nt < 4; ++nt) {
    int n2 = nt * 16 + r16;
    int c_out = hpi * 32 + (n2 >> 3) * 4 + s;
    float gm = gmulL[(nt * 2 + (r16 >> 3)) * 4 + s];
    float* outb = out + (size_t)(b * 256 + c_out) * 4096 + cgh * 8 * 64 + (n2 & 7) * 8;
#pragma unroll
    for (int oti = 0; oti < 2; ++oti) {
      f32x4 a = acc[oti][nt];
      int hh = (half * 2 + oti) * 2 + (g >> 1);
      int wo = (g & 1) * 4;
      f32x4 o4 = {(a.x + tb) * gm, (a.y + tb) * gm,
                  (a.z + tb) * gm, (a.w + tb) * gm};
      __builtin_nontemporal_store(o4, (f32x4*)(outb + hh * 64 + wo));
    }
  }
}

extern "C" void kernel_launch(void* const* d_in, const int* in_sizes, int n_in,
                              void* d_out, int out_size, void* d_ws, size_t ws_size,
                              hipStream_t stream) {
  const float* x     = (const float*)d_in[0];
  const float* fc1_w = (const float*)d_in[1];
  const float* fc1_b = (const float*)d_in[2];
  const float* fc2_w = (const float*)d_in[3];
  const float* fc2_b = (const float*)d_in[4];
  const float* fc3_w = (const float*)d_in[5];
  const float* g3  = (const float*)d_in[6];
  const float* b3  = (const float*)d_in[7];
  const float* m3  = (const float*)d_in[8];
  const float* v3  = (const float*)d_in[9];
  const float* c1w = (const float*)d_in[10];
  const float* g1  = (const float*)d_in[11];
  const float* b1  = (const float*)d_in[12];
  const float* m1  = (const float*)d_in[13];
  const float* v1  = (const float*)d_in[14];
  const float* c3w = (const float*)d_in[15];
  const float* gk  = (const float*)d_in[16];
  const float* bk  = (const float*)d_in[17];
  const float* mk  = (const float*)d_in[18];
  const float* vk  = (const float*)d_in[19];
  float* out = (float*)d_out;

  // ws layout (16B-aligned): pooled 32KB | ahi 32KB | alo 32KB | totb
  float* pooled = (float*)d_ws;
  unsigned short* ahi = (unsigned short*)(pooled + 8192);
  unsigned short* alo = ahi + 16384;
  float* totb   = (float*)(alo + 16384);

  prep_pool_kernel<<<2064, 256, 0, stream>>>(x, pooled, fc3_w, g3, b3, m3, v3,
                                             c1w, g1, b1, m1, v1, c3w, gk, bk,
                                             mk, vk, ahi, alo, totb);
  main_kernel<<<2048, 512, 0, stream>>>(x, ahi, alo, totb, pooled,
                                        fc1_w, fc1_b, fc2_w, fc2_b, out);
}

// Round 13
// 73.317 us; speedup vs baseline: 1.1614x; 1.1614x over previous
//
#include <hip/hip_runtime.h>
#include <math.h>

#define BN_EPS 1e-5f

typedef __attribute__((ext_vector_type(8))) _Float16 half8;
typedef __attribute__((ext_vector_type(4))) float f32x4;

__device__ __forceinline__ unsigned short f16bits(float f) {
  _Float16 h = (_Float16)f;   // HW RNE convert
  return *reinterpret_cast<unsigned short*>(&h);
}

// ---------------- Kernel A: prep (blocks 0..15) + pool (blocks 16..2063) ----
// prep: A_s = sc3*W_s + conv-taps, stored as f16; totb[4].
__global__ __launch_bounds__(256) void prep_pool_kernel(
    const float* __restrict__ x, float* __restrict__ pooled,
    const float* __restrict__ fc3_w,
    const float* __restrict__ g3, const float* __restrict__ b3,
    const float* __restrict__ m3, const float* __restrict__ v3,
    const float* __restrict__ c1w,
    const float* __restrict__ g1, const float* __restrict__ b1,
    const float* __restrict__ m1, const float* __restrict__ v1,
    const float* __restrict__ c3w,
    const float* __restrict__ gk, const float* __restrict__ bk,
    const float* __restrict__ mk, const float* __restrict__ vk,
    unsigned short* __restrict__ af, float* __restrict__ totb) {
  int bid = blockIdx.x;
  int tid = threadIdx.x;
  if (bid < 16) {
    int s = bid >> 2;
    int o = (bid & 3) * 16 + (tid >> 4);
    int kc = (tid & 15) * 4;
    float sc3 = g3[s] * rsqrtf(v3[s] + BN_EPS);
    float sc1 = g1[s] * rsqrtf(v1[s] + BN_EPS);
    float sck = gk[s] * rsqrtf(vk[s] + BN_EPS);
    float c0 = sc1 * c1w[s] + sck * c3w[s * 9 + 4];
    int oh = o >> 3, ow = o & 7;
    unsigned short H[4];
#pragma unroll
    for (int j = 0; j < 4; ++j) {
      int k = kc + j;
      int kh = k >> 3, kw = k & 7;
      float a = sc3 * fc3_w[(s * 64 + o) * 64 + k];
      int dy = kh - oh, dx = kw - ow;
      if (dy >= -1 && dy <= 1 && dx >= -1 && dx <= 1)
        a += (dy == 0 && dx == 0) ? c0 : sck * c3w[s * 9 + (dy + 1) * 3 + (dx + 1)];
      H[j] = f16bits(a);
    }
    size_t base = (size_t)(s * 64 + o) * 64 + kc;
    *(ushort4*)(af + base) = make_ushort4(H[0], H[1], H[2], H[3]);
    if (bid == 0 && tid < 4) {
      int ss = tid;
      float s3 = g3[ss] * rsqrtf(v3[ss] + BN_EPS);
      float s1 = g1[ss] * rsqrtf(v1[ss] + BN_EPS);
      float sk = gk[ss] * rsqrtf(vk[ss] + BN_EPS);
      totb[ss] = (b3[ss] - m3[ss] * s3) + (b1[ss] - m1[ss] * s1) + (bk[ss] - mk[ss] * sk);
    }
    return;
  }
  int w = tid >> 6, lane = tid & 63;
  int bc = (bid - 16) * 4 + w;
  const f32x4* xp = (const f32x4*)(x + (size_t)bc * 4096);
  float ssum = 0.f;
#pragma unroll
  for (int i = 0; i < 16; ++i) {
    f32x4 v = xp[i * 64 + lane];
    ssum += (v.x + v.y) + (v.z + v.w);
  }
#pragma unroll
  for (int m = 32; m >= 1; m >>= 1) ssum += __shfl_xor(ssum, m, 64);
  if (lane == 0) pooled[bc] = ssum * (1.f / 4096.f);
}

// ---------------- Kernel B: gate MLP (tiny, traffic-shared) ----------------
__global__ __launch_bounds__(256) void gate_kernel(const float* __restrict__ pooled,
                                                   const float* __restrict__ fc1_w,
                                                   const float* __restrict__ fc1_b,
                                                   const float* __restrict__ fc2_w,
                                                   const float* __restrict__ fc2_b,
                                                   float* __restrict__ gate) {
  int b = blockIdx.x;
  int tid = threadIdx.x;
  __shared__ float p[256];
  __shared__ float hbuf[64];
  p[tid] = pooled[b * 256 + tid];
  __syncthreads();
  if (tid < 64) {
    float a = fc1_b[tid];
    const float* wr = fc1_w + tid * 256;
#pragma unroll 8
    for (int c = 0; c < 256; ++c) a += p[c] * wr[c];
    hbuf[tid] = fmaxf(a, 0.f);
  }
  __syncthreads();
  float g = fc2_b[tid];
  const float* w2 = fc2_w + tid * 64;
#pragma unroll 8
  for (int j = 0; j < 64; ++j) g += hbuf[j] * w2[j];
  gate[b * 256 + tid] = 1.f / (1.f + expf(-g));
}

// ---------------- Kernel C: main — LDS-staged f16 MFMA (single plane) -----
// Grid 2048 = (b, hpi, cgh). Block = 512 thr = 8 waves = (s x o-half).
// Stage: coalesced fp32 tile loads -> f16 -> slot-padded LDS (stride 520).
// MFMA loop: 8 ds_read_b128 + 16 mfma_f32_16x16x32_f16 per wave. NT stores.
__global__ __launch_bounds__(512, 2) void main_kernel(
    const float* __restrict__ x,
    const unsigned short* __restrict__ af,
    const float* __restrict__ totb, const float* __restrict__ gate,
    float* __restrict__ out) {
  __shared__ unsigned short xs[16640];  // 32 slots x 520 (f16 bits)

  int bid = blockIdx.x;
  int cgh = bid & 7;
  int hpi = (bid >> 3) & 7;
  int b   = bid >> 6;
  int tid = threadIdx.x;
  int wv  = tid >> 6;
  int s    = __builtin_amdgcn_readfirstlane(wv & 3);
  int half = __builtin_amdgcn_readfirstlane(wv >> 2);
  int r16 = tid & 15;
  int g   = (tid >> 4) & 3;

  // ---- stage: 8 batched contiguous loads per thread ----
  f32x4 gbuf[8];
#pragma unroll
  for (int i = 0; i < 8; ++i) {
    int flat = i * 512 + tid;
    int slot = flat >> 7;
    int off  = flat & 127;
    int row  = off >> 4, w4 = off & 15;
    int c = cgh * 32 + (slot & 7) * 4 + (slot >> 3);
    gbuf[i] = *(const f32x4*)(x + (size_t)(b * 256 + c) * 4096 + (hpi * 8 + row) * 64 + w4 * 4);
  }

  // ---- A fragments + gate + bias issued while staging loads fly ----
  half8 Af[2][2];  // [kt][oti], rows (half*2+oti)*16+r16
#pragma unroll
  for (int oti = 0; oti < 2; ++oti)
#pragma unroll
    for (int kt = 0; kt < 2; ++kt) {
      size_t off = (size_t)(s * 64 + (half * 2 + oti) * 16 + r16) * 64 + kt * 32 + g * 8;
      Af[kt][oti] = *(const half8*)(af + off);
    }
  float gmul[4];
#pragma unroll
  for (int nt = 0; nt < 4; ++nt)
    gmul[nt] = gate[b * 256 + hpi * 32 + (nt * 2 + (r16 >> 3)) * 4 + s];
  float tb = totb[s];

  // ---- convert + ds_write (single f16 plane) ----
#pragma unroll
  for (int i = 0; i < 8; ++i) {
    int flat = i * 512 + tid;
    int slot = flat >> 7;
    int off  = flat & 127;
    int row  = off >> 4, w4 = off & 15;
    ushort4 H = make_ushort4(f16bits(gbuf[i].x), f16bits(gbuf[i].y),
                             f16bits(gbuf[i].z), f16bits(gbuf[i].w));
    *(ushort4*)&xs[slot * 520 + row * 64 + w4 * 4] = H;
  }

  __syncthreads();

  // ---- MFMA loop: pure ds_read + MFMA ----
  f32x4 acc[2][4];
#pragma unroll
  for (int i = 0; i < 2; ++i)
#pragma unroll
    for (int j = 0; j < 4; ++j) acc[i][j] = f32x4{0.f, 0.f, 0.f, 0.f};

  int jch = r16 & 7;
#pragma unroll
  for (int kt = 0; kt < 2; ++kt)
#pragma unroll
    for (int nt = 0; nt < 4; ++nt) {
      int wpi = nt * 2 + (r16 >> 3);
      int addr = (s * 8 + jch) * 520 + (kt * 4 + g) * 64 + wpi * 8;
      half8 Bv = *(const half8*)&xs[addr];
#pragma unroll
      for (int oti = 0; oti < 2; ++oti)
        acc[oti][nt] = __builtin_amdgcn_mfma_f32_16x16x32_f16(Af[kt][oti], Bv, acc[oti][nt], 0, 0, 0);
    }

  // ---- epilogue: NT stores. o = (half*2+oti)*16 + g*4 + r, col n2 = nt*16+r16
#pragma unroll
  for (int nt = 0; nt < 4; ++nt) {
    int n2 = nt * 16 + r16;
    int c_out = hpi * 32 + (n2 >> 3) * 4 + s;
    float gm = gmul[nt];
    float* outb = out + (size_t)(b * 256 + c_out) * 4096 + cgh * 8 * 64 + (n2 & 7) * 8;
#pragma unroll
    for (int oti = 0; oti < 2; ++oti) {
      f32x4 a = acc[oti][nt];
      int hh = (half * 2 + oti) * 2 + (g >> 1);
      int wo = (g & 1) * 4;
      f32x4 o4 = {(a.x + tb) * gm, (a.y + tb) * gm,
                  (a.z + tb) * gm, (a.w + tb) * gm};
      __builtin_nontemporal_store(o4, (f32x4*)(outb + hh * 64 + wo));
    }
  }
}

extern "C" void kernel_launch(void* const* d_in, const int* in_sizes, int n_in,
                              void* d_out, int out_size, void* d_ws, size_t ws_size,
                              hipStream_t stream) {
  const float* x     = (const float*)d_in[0];
  const float* fc1_w = (const float*)d_in[1];
  const float* fc1_b = (const float*)d_in[2];
  const float* fc2_w = (const float*)d_in[3];
  const float* fc2_b = (const float*)d_in[4];
  const float* fc3_w = (const float*)d_in[5];
  const float* g3  = (const float*)d_in[6];
  const float* b3  = (const float*)d_in[7];
  const float* m3  = (const float*)d_in[8];
  const float* v3  = (const float*)d_in[9];
  const float* c1w = (const float*)d_in[10];
  const float* g1  = (const float*)d_in[11];
  const float* b1  = (const float*)d_in[12];
  const float* m1  = (const float*)d_in[13];
  const float* v1  = (const float*)d_in[14];
  const float* c3w = (const float*)d_in[15];
  const float* gk  = (const float*)d_in[16];
  const float* bk  = (const float*)d_in[17];
  const float* mk  = (const float*)d_in[18];
  const float* vk  = (const float*)d_in[19];
  float* out = (float*)d_out;

  // ws layout (16B-aligned): pooled 32KB | gate 32KB | af 32KB | totb
  float* pooled = (float*)d_ws;
  float* gate   = pooled + 8192;
  unsigned short* af = (unsigned short*)(gate + 8192);
  float* totb   = (float*)(af + 16384);

  prep_pool_kernel<<<2064, 256, 0, stream>>>(x, pooled, fc3_w, g3, b3, m3, v3,
                                             c1w, g1, b1, m1, v1, c3w, gk, bk,
                                             mk, vk, af, totb);
  gate_kernel<<<32, 256, 0, stream>>>(pooled, fc1_w, fc1_b, fc2_w, fc2_b, gate);
  main_kernel<<<2048, 512, 0, stream>>>(x, af, totb, gate, out);
}

// Round 14
// 73.183 us; speedup vs baseline: 1.1636x; 1.0018x over previous
//
#include <hip/hip_runtime.h>
#include <math.h>

#define BN_EPS 1e-5f

typedef __attribute__((ext_vector_type(8))) _Float16 half8;
typedef __attribute__((ext_vector_type(4))) float f32x4;

__device__ __forceinline__ unsigned short f16bits(float f) {
  _Float16 h = (_Float16)f;   // HW RNE convert
  return *reinterpret_cast<unsigned short*>(&h);
}

// ---------------- Kernel A: prep (blocks 0..15) + pool (blocks 16..2063) ----
// prep: A_s = sc3*W_s + conv-taps, stored as f16; totb[4].
// pool planes processed in REVERSE order: leaves x's head (b=0) L3-hottest,
// matching main's dispatch order (which starts at b=0).
__global__ __launch_bounds__(256) void prep_pool_kernel(
    const float* __restrict__ x, float* __restrict__ pooled,
    const float* __restrict__ fc3_w,
    const float* __restrict__ g3, const float* __restrict__ b3,
    const float* __restrict__ m3, const float* __restrict__ v3,
    const float* __restrict__ c1w,
    const float* __restrict__ g1, const float* __restrict__ b1,
    const float* __restrict__ m1, const float* __restrict__ v1,
    const float* __restrict__ c3w,
    const float* __restrict__ gk, const float* __restrict__ bk,
    const float* __restrict__ mk, const float* __restrict__ vk,
    unsigned short* __restrict__ af, float* __restrict__ totb) {
  int bid = blockIdx.x;
  int tid = threadIdx.x;
  if (bid < 16) {
    int s = bid >> 2;
    int o = (bid & 3) * 16 + (tid >> 4);
    int kc = (tid & 15) * 4;
    float sc3 = g3[s] * rsqrtf(v3[s] + BN_EPS);
    float sc1 = g1[s] * rsqrtf(v1[s] + BN_EPS);
    float sck = gk[s] * rsqrtf(vk[s] + BN_EPS);
    float c0 = sc1 * c1w[s] + sck * c3w[s * 9 + 4];
    int oh = o >> 3, ow = o & 7;
    unsigned short H[4];
#pragma unroll
    for (int j = 0; j < 4; ++j) {
      int k = kc + j;
      int kh = k >> 3, kw = k & 7;
      float a = sc3 * fc3_w[(s * 64 + o) * 64 + k];
      int dy = kh - oh, dx = kw - ow;
      if (dy >= -1 && dy <= 1 && dx >= -1 && dx <= 1)
        a += (dy == 0 && dx == 0) ? c0 : sck * c3w[s * 9 + (dy + 1) * 3 + (dx + 1)];
      H[j] = f16bits(a);
    }
    size_t base = (size_t)(s * 64 + o) * 64 + kc;
    *(ushort4*)(af + base) = make_ushort4(H[0], H[1], H[2], H[3]);
    if (bid == 0 && tid < 4) {
      int ss = tid;
      float s3 = g3[ss] * rsqrtf(v3[ss] + BN_EPS);
      float s1 = g1[ss] * rsqrtf(v1[ss] + BN_EPS);
      float sk = gk[ss] * rsqrtf(vk[ss] + BN_EPS);
      totb[ss] = (b3[ss] - m3[ss] * s3) + (b1[ss] - m1[ss] * s1) + (bk[ss] - mk[ss] * sk);
    }
    return;
  }
  int w = tid >> 6, lane = tid & 63;
  int bc = 8191 - ((bid - 16) * 4 + w);   // reversed plane order
  const f32x4* xp = (const f32x4*)(x + (size_t)bc * 4096);
  float ssum = 0.f;
#pragma unroll
  for (int i = 0; i < 16; ++i) {
    f32x4 v = xp[i * 64 + lane];
    ssum += (v.x + v.y) + (v.z + v.w);
  }
#pragma unroll
  for (int m = 32; m >= 1; m >>= 1) ssum += __shfl_xor(ssum, m, 64);
  if (lane == 0) pooled[bc] = ssum * (1.f / 4096.f);
}

// ---------------- Kernel B: gate MLP (tiny, traffic-shared) ----------------
__global__ __launch_bounds__(256) void gate_kernel(const float* __restrict__ pooled,
                                                   const float* __restrict__ fc1_w,
                                                   const float* __restrict__ fc1_b,
                                                   const float* __restrict__ fc2_w,
                                                   const float* __restrict__ fc2_b,
                                                   float* __restrict__ gate) {
  int b = blockIdx.x;
  int tid = threadIdx.x;
  __shared__ float p[256];
  __shared__ float hbuf[64];
  p[tid] = pooled[b * 256 + tid];
  __syncthreads();
  if (tid < 64) {
    float a = fc1_b[tid];
    const float* wr = fc1_w + tid * 256;
#pragma unroll 8
    for (int c = 0; c < 256; ++c) a += p[c] * wr[c];
    hbuf[tid] = fmaxf(a, 0.f);
  }
  __syncthreads();
  float g = fc2_b[tid];
  const float* w2 = fc2_w + tid * 64;
#pragma unroll 8
  for (int j = 0; j < 64; ++j) g += hbuf[j] * w2[j];
  gate[b * 256 + tid] = 1.f / (1.f + expf(-g));
}

// ---------------- Kernel C: main — LDS-staged f16 MFMA (single plane) -----
// Grid 2048 = (b, hpi, cgh). Block = 512 thr = 8 waves = (s x o-half).
// Stage: coalesced fp32 tile loads -> f16 -> slot-padded LDS (stride 520).
// MFMA loop: 8 ds_read_b128 + 16 mfma_f32_16x16x32_f16 per wave. NT stores.
__global__ __launch_bounds__(512, 2) void main_kernel(
    const float* __restrict__ x,
    const unsigned short* __restrict__ af,
    const float* __restrict__ totb, const float* __restrict__ gate,
    float* __restrict__ out) {
  __shared__ unsigned short xs[16640];  // 32 slots x 520 (f16 bits)

  int bid = blockIdx.x;
  int cgh = bid & 7;
  int hpi = (bid >> 3) & 7;
  int b   = bid >> 6;
  int tid = threadIdx.x;
  int wv  = tid >> 6;
  int s    = __builtin_amdgcn_readfirstlane(wv & 3);
  int half = __builtin_amdgcn_readfirstlane(wv >> 2);
  int r16 = tid & 15;
  int g   = (tid >> 4) & 3;

  // ---- stage: 8 batched contiguous loads per thread ----
  f32x4 gbuf[8];
#pragma unroll
  for (int i = 0; i < 8; ++i) {
    int flat = i * 512 + tid;
    int slot = flat >> 7;
    int off  = flat & 127;
    int row  = off >> 4, w4 = off & 15;
    int c = cgh * 32 + (slot & 7) * 4 + (slot >> 3);
    gbuf[i] = *(const f32x4*)(x + (size_t)(b * 256 + c) * 4096 + (hpi * 8 + row) * 64 + w4 * 4);
  }

  // ---- A fragments + gate + bias issued while staging loads fly ----
  half8 Af[2][2];  // [kt][oti], rows (half*2+oti)*16+r16
#pragma unroll
  for (int oti = 0; oti < 2; ++oti)
#pragma unroll
    for (int kt = 0; kt < 2; ++kt) {
      size_t off = (size_t)(s * 64 + (half * 2 + oti) * 16 + r16) * 64 + kt * 32 + g * 8;
      Af[kt][oti] = *(const half8*)(af + off);
    }
  float gmul[4];
#pragma unroll
  for (int nt = 0; nt < 4; ++nt)
    gmul[nt] = gate[b * 256 + hpi * 32 + (nt * 2 + (r16 >> 3)) * 4 + s];
  float tb = totb[s];

  // ---- convert + ds_write (single f16 plane) ----
#pragma unroll
  for (int i = 0; i < 8; ++i) {
    int flat = i * 512 + tid;
    int slot = flat >> 7;
    int off  = flat & 127;
    int row  = off >> 4, w4 = off & 15;
    ushort4 H = make_ushort4(f16bits(gbuf[i].x), f16bits(gbuf[i].y),
                             f16bits(gbuf[i].z), f16bits(gbuf[i].w));
    *(ushort4*)&xs[slot * 520 + row * 64 + w4 * 4] = H;
  }

  __syncthreads();

  // ---- MFMA loop: pure ds_read + MFMA ----
  f32x4 acc[2][4];
#pragma unroll
  for (int i = 0; i < 2; ++i)
#pragma unroll
    for (int j = 0; j < 4; ++j) acc[i][j] = f32x4{0.f, 0.f, 0.f, 0.f};

  int jch = r16 & 7;
#pragma unroll
  for (int kt = 0; kt < 2; ++kt)
#pragma unroll
    for (int nt = 0; nt < 4; ++nt) {
      int wpi = nt * 2 + (r16 >> 3);
      int addr = (s * 8 + jch) * 520 + (kt * 4 + g) * 64 + wpi * 8;
      half8 Bv = *(const half8*)&xs[addr];
#pragma unroll
      for (int oti = 0; oti < 2; ++oti)
        acc[oti][nt] = __builtin_amdgcn_mfma_f32_16x16x32_f16(Af[kt][oti], Bv, acc[oti][nt], 0, 0, 0);
    }

  // ---- epilogue: NT stores. o = (half*2+oti)*16 + g*4 + r, col n2 = nt*16+r16
#pragma unroll
  for (int nt = 0; nt < 4; ++nt) {
    int n2 = nt * 16 + r16;
    int c_out = hpi * 32 + (n2 >> 3) * 4 + s;
    float gm = gmul[nt];
    float* outb = out + (size_t)(b * 256 + c_out) * 4096 + cgh * 8 * 64 + (n2 & 7) * 8;
#pragma unroll
    for (int oti = 0; oti < 2; ++oti) {
      f32x4 a = acc[oti][nt];
      int hh = (half * 2 + oti) * 2 + (g >> 1);
      int wo = (g & 1) * 4;
      f32x4 o4 = {(a.x + tb) * gm, (a.y + tb) * gm,
                  (a.z + tb) * gm, (a.w + tb) * gm};
      __builtin_nontemporal_store(o4, (f32x4*)(outb + hh * 64 + wo));
    }
  }
}

extern "C" void kernel_launch(void* const* d_in, const int* in_sizes, int n_in,
                              void* d_out, int out_size, void* d_ws, size_t ws_size,
                              hipStream_t stream) {
  const float* x     = (const float*)d_in[0];
  const float* fc1_w = (const float*)d_in[1];
  const float* fc1_b = (const float*)d_in[2];
  const float* fc2_w = (const float*)d_in[3];
  const float* fc2_b = (const float*)d_in[4];
  const float* fc3_w = (const float*)d_in[5];
  const float* g3  = (const float*)d_in[6];
  const float* b3  = (const float*)d_in[7];
  const float* m3  = (const float*)d_in[8];
  const float* v3  = (const float*)d_in[9];
  const float* c1w = (const float*)d_in[10];
  const float* g1  = (const float*)d_in[11];
  const float* b1  = (const float*)d_in[12];
  const float* m1  = (const float*)d_in[13];
  const float* v1  = (const float*)d_in[14];
  const float* c3w = (const float*)d_in[15];
  const float* gk  = (const float*)d_in[16];
  const float* bk  = (const float*)d_in[17];
  const float* mk  = (const float*)d_in[18];
  const float* vk  = (const float*)d_in[19];
  float* out = (float*)d_out;

  // ws layout (16B-aligned): pooled 32KB | gate 32KB | af 32KB | totb
  float* pooled = (float*)d_ws;
  float* gate   = pooled + 8192;
  unsigned short* af = (unsigned short*)(gate + 8192);
  float* totb   = (float*)(af + 16384);

  prep_pool_kernel<<<2064, 256, 0, stream>>>(x, pooled, fc3_w, g3, b3, m3, v3,
                                             c1w, g1, b1, m1, v1, c3w, gk, bk,
                                             mk, vk, af, totb);
  gate_kernel<<<32, 256, 0, stream>>>(pooled, fc1_w, fc1_b, fc2_w, fc2_b, gate);
  main_kernel<<<2048, 512, 0, stream>>>(x, af, totb, gate, out);
}